// Round 2
// baseline (381.292 us; speedup 1.0000x reference)
//
#include <hip/hip_runtime.h>

typedef _Float16 half8   __attribute__((ext_vector_type(8)));
typedef float    floatx16 __attribute__((ext_vector_type(16)));
typedef float    float4v  __attribute__((ext_vector_type(4)));

#define K_DIM 256
#define N_DIM 256
#define BM    32
#define TPB   8
#define NBLK  2048     // NBLK * TPB * BM = 524288 rows

// Build W^T in f16 bit patterns: W[k][n] = 2^shift[k][n] * (-1)^sign[k][n].
// shift is an exact integer in [-10,-1]; 2^shift is exact in f16.
__global__ __launch_bounds__(256) void build_wT(const float* __restrict__ shift,
                                                const float* __restrict__ sgn,
                                                unsigned short* __restrict__ wT) {
    int idx = blockIdx.x * 256 + threadIdx.x;   // idx = k*256 + n
    int k = idx >> 8, n = idx & 255;
    float sh = shift[idx];
    float sg = sgn[idx];
    int e = 15 + (int)sh;                       // f16 exponent field, 5..14
    unsigned short wv = (unsigned short)(((sg != 0.0f) ? 0x8000 : 0) | (e << 10));
    wT[n * 256 + k] = wv;                       // W^T[n][k], contiguous K
}

__global__ __launch_bounds__(512, 4) void dense_shift_gemm(
        const float* __restrict__ x,
        const unsigned short* __restrict__ wT,
        const float* __restrict__ bias,
        float* __restrict__ out) {

    // Double-buffered A tile, f16, full-row XOR swizzle: 16B-slot s -> s ^ (row&31).
    // Bijective per row; both ds_write_b128 and ds_read_b128 land 2-way (free).
    __shared__ __align__(16) unsigned short aLds[2][BM * K_DIM];   // 2 x 16 KB

    const int t  = threadIdx.x;
    const int w  = t >> 6;            // wave 0..7 -> output cols [w*32, w*32+32)
    const int l  = t & 63;
    const int ln = l & 31;
    const int hi = l >> 5;

    const long rowblock0 = (long)blockIdx.x * (TPB * BM);

    // ---- staging geometry: thread stages row srow, 16 consecutive floats ----
    const int srow = t >> 4;                  // 0..31
    const int sj   = t & 15;
    const float* xb = x + (rowblock0 + srow) * (long)K_DIM + sj * 16;
    char* ldsb = (char*)&aLds[0][0];
    const int wb0 = srow * 512 + (((sj * 2)     ^ srow) << 4);
    const int wb1 = srow * 512 + (((sj * 2 + 1) ^ srow) << 4);

    // ---- compute geometry (mfma_f32_32x32x16_f16) ----
    // A lane: row = l&31, k = (l>>5)*8 + j   (slot_raw = 2*ks + hi, swizzle ^row)
    // B lane: col = l&31, k = (l>>5)*8 + j
    // C lane: col = l&31, row = (r&3) + 8*(r>>2) + 4*(l>>5)
    const int hr    = hi ^ ln;                // fold hi into the row-XOR
    const int abase = ln * 512;               // A row byte base in LDS
    const char* bp  = (const char*)(wT + (long)(w * 32 + ln) * K_DIM + hi * 8);
    const float bv  = bias[w * 32 + ln];
    float* ob = out + (rowblock0 + 4 * hi) * (long)N_DIM + w * 32 + ln;

    float4v L0, L1, L2, L3;

#define ISSUE(tt) do {                                          \
        const float* p_ = xb + (long)(tt) * (BM * K_DIM);       \
        L0 = *(const float4v*)(p_);                             \
        L1 = *(const float4v*)(p_ + 4);                         \
        L2 = *(const float4v*)(p_ + 8);                         \
        L3 = *(const float4v*)(p_ + 12);                        \
    } while (0)

#define CVT_WRITE(wbase_) do {                                  \
        half8 h0_, h1_;                                         \
        h0_[0]=(_Float16)L0[0]; h0_[1]=(_Float16)L0[1];         \
        h0_[2]=(_Float16)L0[2]; h0_[3]=(_Float16)L0[3];         \
        h0_[4]=(_Float16)L1[0]; h0_[5]=(_Float16)L1[1];         \
        h0_[6]=(_Float16)L1[2]; h0_[7]=(_Float16)L1[3];         \
        h1_[0]=(_Float16)L2[0]; h1_[1]=(_Float16)L2[1];         \
        h1_[2]=(_Float16)L2[2]; h1_[3]=(_Float16)L2[3];         \
        h1_[4]=(_Float16)L3[0]; h1_[5]=(_Float16)L3[1];         \
        h1_[6]=(_Float16)L3[2]; h1_[7]=(_Float16)L3[3];         \
        *(half8*)(ldsb + (wbase_) + wb0) = h0_;                 \
        *(half8*)(ldsb + (wbase_) + wb1) = h1_;                 \
    } while (0)

    // ---- prologue: fill buf0 (tile 0), issue tile 1 ----
    ISSUE(0);
    CVT_WRITE(0);
    ISSUE(1);
    asm volatile("s_waitcnt lgkmcnt(0)" ::: "memory");
    __builtin_amdgcn_s_barrier();

    // ---- continuous tile pipeline: one raw barrier per tile, x-prefetch
    //      loads stay in flight across barriers (no vmcnt(0) drain) ----
    for (int tt = 0; tt < TPB; ++tt) {
        const int cbase = (tt & 1) << 14;      // current 16 KB buffer

        floatx16 acc = {0,0,0,0,0,0,0,0,0,0,0,0,0,0,0,0};
#pragma unroll
        for (int ks = 0; ks < 16; ++ks) {
            const int ab = abase + (((2 * ks) ^ hr) << 4);
            half8 a_ = *(const half8*)(ldsb + cbase + ab);
            half8 b_ = *(const half8*)(bp + ks * 32);          // L1/L2-resident W^T
            acc = __builtin_amdgcn_mfma_f32_32x32x16_f16(a_, b_, acc, 0, 0, 0);
        }

        if (tt + 1 < TPB) CVT_WRITE(((tt + 1) & 1) << 14);     // stage tile tt+1
        if (tt + 2 < TPB) ISSUE(tt + 2);                       // prefetch tile tt+2

        // store tile tt (fire-and-forget)
        {
            float* o_ = ob + (long)tt * (BM * N_DIM);
#pragma unroll
            for (int r = 0; r < 16; ++r) {
                const int row = (r & 3) + 8 * (r >> 2);
                o_[(long)row * N_DIM] = acc[r] + bv;
            }
        }

        if (tt + 1 < TPB) {
            asm volatile("s_waitcnt lgkmcnt(0)" ::: "memory");
            __builtin_amdgcn_s_barrier();
        }
    }

#undef ISSUE
#undef CVT_WRITE
}

extern "C" void kernel_launch(void* const* d_in, const int* in_sizes, int n_in,
                              void* d_out, int out_size, void* d_ws, size_t ws_size,
                              hipStream_t stream) {
    const float* x     = (const float*)d_in[0];
    const float* shift = (const float*)d_in[1];
    const float* sgn   = (const float*)d_in[2];
    const float* bias  = (const float*)d_in[3];
    float* out = (float*)d_out;
    unsigned short* wT = (unsigned short*)d_ws;   // 256*256*2 = 128 KB scratch

    build_wT<<<256, 256, 0, stream>>>(shift, sgn, wT);
    dense_shift_gemm<<<NBLK, 512, 0, stream>>>(x, wT, bias, out);
}